// Round 1
// baseline (452.013 us; speedup 1.0000x reference)
//
#include <hip/hip_runtime.h>
#include <cstdint>
#include <cstddef>

// Problem constants (from reference)
static constexpr int Bn   = 16384;
static constexpr int INn  = 1024;
static constexpr int HIDn = 2048;
static constexpr int OUTn = 256;
static constexpr int NGn  = 8;
static constexpr int MAXT = 136;   // max M-tiles over all groups: B/128 + G

typedef __attribute__((ext_vector_type(8))) __bf16 bf16x8;
typedef __attribute__((ext_vector_type(4))) float  f32x4;

__device__ __forceinline__ unsigned short f2bf(float f) {
  unsigned int u = __builtin_bit_cast(unsigned int, f);
  u += 0x7fffu + ((u >> 16) & 1u);   // RNE
  return (unsigned short)(u >> 16);
}

__device__ __forceinline__ void load_lds16(const void* g, void* l) {
  __builtin_amdgcn_global_load_lds(
      (const __attribute__((address_space(1))) unsigned int*)g,
      (__attribute__((address_space(3))) unsigned int*)l, 16, 0, 0);
}

// ---------------- routing kernels ----------------
__global__ void hist_k(const int* __restrict__ gid, int* __restrict__ cnt) {
  int i = blockIdx.x * blockDim.x + threadIdx.x;
  if (i < Bn) atomicAdd(&cnt[gid[i]], 1);
}

__global__ void scan_desc_k(const int* __restrict__ cnt, int* __restrict__ goff,
                            int* __restrict__ fill, int* __restrict__ ntiles,
                            int2* __restrict__ desc) {
  if (threadIdx.x == 0 && blockIdx.x == 0) {
    int o = 0, nt = 0;
    for (int g = 0; g < NGn; g++) {
      goff[g] = o;
      int c = cnt[g];
      for (int m = 0; m < c; m += 128) { desc[nt].x = g; desc[nt].y = m; nt++; }
      o += c;
      fill[g] = 0;
    }
    *ntiles = nt;
  }
}

__global__ void scatter_k(const int* __restrict__ gid, const int* __restrict__ goff,
                          int* __restrict__ fill, int* __restrict__ ridx) {
  int i = blockIdx.x * blockDim.x + threadIdx.x;
  if (i < Bn) {
    int g = gid[i];
    int pos = goff[g] + atomicAdd(&fill[g], 1);
    ridx[pos] = i;   // order nondeterministic, output values invariant
  }
}

// ---------------- conversion kernels ----------------
__global__ void conv_bf16_k(const float* __restrict__ src, unsigned short* __restrict__ dst,
                            int nvec) {  // nvec = elements/4
  int i = blockIdx.x * blockDim.x + threadIdx.x;
  int stride = gridDim.x * blockDim.x;
  for (; i < nvec; i += stride) {
    float4 v = ((const float4*)src)[i];
    uint2 o;
    o.x = (unsigned)f2bf(v.x) | ((unsigned)f2bf(v.y) << 16);
    o.y = (unsigned)f2bf(v.z) | ((unsigned)f2bf(v.w) << 16);
    ((uint2*)dst)[i] = o;
  }
}

// src [K][N] f32 row-major -> dst [N][K] bf16 row-major; blockIdx.z = batch
__global__ void transpose_k(const float* __restrict__ src, unsigned short* __restrict__ dst,
                            int K, int N) {
  __shared__ float t[32][33];
  size_t bo = (size_t)blockIdx.z * (size_t)K * (size_t)N;
  int n0 = blockIdx.x * 32, k0 = blockIdx.y * 32;
  #pragma unroll
  for (int i = 0; i < 32; i += 8)
    t[threadIdx.y + i][threadIdx.x] =
        src[bo + (size_t)(k0 + threadIdx.y + i) * N + n0 + threadIdx.x];
  __syncthreads();
  #pragma unroll
  for (int i = 0; i < 32; i += 8)
    dst[bo + (size_t)(n0 + threadIdx.y + i) * K + k0 + threadIdx.x] =
        f2bf(t[threadIdx.x][threadIdx.y + i]);
}

// ---------------- GEMM ----------------
// C[M,N] = act(A[M,K](bf16) @ Bt[N,K]^T(bf16) + bias), 128x128 tile, BK=64,
// 4 waves of 4x4 16x16x32 fragments. XOR-swizzled LDS (G4: stride 128B rows).
template <bool GROUPED, bool GATHER_A, bool SCATTER_C, bool RELU_BF16>
__global__ __launch_bounds__(256, 2) void gemm_k(
    const unsigned short* __restrict__ A, const unsigned short* __restrict__ Bt,
    const float* __restrict__ bias, void* __restrict__ Cout, int K, int N,
    const int* __restrict__ cnt, const int* __restrict__ goff,
    const int* __restrict__ ntiles, const int2* __restrict__ desc,
    const int* __restrict__ ridx) {
  int row0, cnt_rem;
  if constexpr (GROUPED) {
    if ((int)blockIdx.x >= *ntiles) return;
    int2 d = desc[blockIdx.x];
    int g = d.x;
    row0 = goff[g] + d.y;
    cnt_rem = cnt[g] - d.y;
    Bt += (size_t)g * (size_t)K * (size_t)N;
    bias += (size_t)g * (size_t)N;
  } else {
    row0 = blockIdx.x * 128;
    cnt_rem = 128;
  }
  int n0 = blockIdx.y * 128;

  __shared__ __align__(16) char lds[32768];  // A: [0,16K) B^T: [16K,32K)

  int t = threadIdx.x;
  int lane = t & 63, wid = t >> 6;

  // staging source pointers (4 issues per matrix; row/col fixed across K-steps)
  const unsigned short* pA[4];
  const unsigned short* pB[4];
  #pragma unroll
  for (int i = 0; i < 4; i++) {
    int r = i * 32 + (t >> 3);             // logical tile row for this lane's 16B
    int cg = (t & 7) ^ (r & 7);            // inverse-swizzled column granule
    int rA;
    if constexpr (GROUPED) {
      int rcl = r < cnt_rem ? r : cnt_rem - 1;
      if constexpr (GATHER_A) rA = ridx[row0 + rcl];
      else                    rA = row0 + rcl;
    } else {
      rA = row0 + r;
    }
    pA[i] = A + (size_t)rA * K + cg * 8;
    pB[i] = Bt + (size_t)(n0 + r) * K + cg * 8;
  }

  int ln15 = lane & 15, l16 = lane >> 4, ln7 = lane & 7;
  int wm = wid >> 1, wn = wid & 1;
  int aoffb[4], boffb[4];
  #pragma unroll
  for (int m = 0; m < 4; m++) aoffb[m] = (wm * 64 + m * 16 + ln15) << 7;
  #pragma unroll
  for (int n = 0; n < 4; n++) boffb[n] = ((wn * 64 + n * 16 + ln15) << 7) + 16384;
  const int gsw0 = (l16 ^ ln7) << 4;
  const int gsw1 = ((4 + l16) ^ ln7) << 4;

  f32x4 acc[4][4];
  #pragma unroll
  for (int m = 0; m < 4; m++)
    #pragma unroll
    for (int n = 0; n < 4; n++) acc[m][n] = {0.f, 0.f, 0.f, 0.f};

  for (int kt = 0; kt < K; kt += 64) {
    __syncthreads();
    #pragma unroll
    for (int i = 0; i < 4; i++)
      load_lds16(pA[i] + kt, lds + i * 4096 + wid * 1024);
    #pragma unroll
    for (int i = 0; i < 4; i++)
      load_lds16(pB[i] + kt, lds + 16384 + i * 4096 + wid * 1024);
    __syncthreads();  // compiler drains vmcnt(0) before this barrier
    #pragma unroll
    for (int ks = 0; ks < 2; ks++) {
      const int gsw = ks ? gsw1 : gsw0;
      bf16x8 av[4], bv[4];
      #pragma unroll
      for (int m = 0; m < 4; m++) av[m] = *(const bf16x8*)(lds + aoffb[m] + gsw);
      #pragma unroll
      for (int n = 0; n < 4; n++) bv[n] = *(const bf16x8*)(lds + boffb[n] + gsw);
      #pragma unroll
      for (int m = 0; m < 4; m++)
        #pragma unroll
        for (int n = 0; n < 4; n++)
          acc[m][n] = __builtin_amdgcn_mfma_f32_16x16x32_bf16(av[m], bv[n], acc[m][n], 0, 0, 0);
    }
  }

  float biasv[4];
  #pragma unroll
  for (int n = 0; n < 4; n++) biasv[n] = bias[n0 + wn * 64 + n * 16 + ln15];

  #pragma unroll
  for (int m = 0; m < 4; m++) {
    #pragma unroll
    for (int j = 0; j < 4; j++) {
      int r = wm * 64 + m * 16 + l16 * 4 + j;   // C row within tile
      if (GROUPED && r >= cnt_rem) continue;
      size_t orow;
      if constexpr (SCATTER_C) orow = (size_t)ridx[row0 + r];
      else                     orow = (size_t)(row0 + r);
      #pragma unroll
      for (int n = 0; n < 4; n++) {
        int col = n0 + wn * 64 + n * 16 + ln15;
        float v = acc[m][n][j] + biasv[n];
        if constexpr (RELU_BF16) {
          v = v > 0.f ? v : 0.f;
          ((unsigned short*)Cout)[orow * N + col] = f2bf(v);
        } else {
          ((float*)Cout)[orow * N + col] = v;
        }
      }
    }
  }
}

// ---------------- launch ----------------
extern "C" void kernel_launch(void* const* d_in, const int* in_sizes, int n_in,
                              void* d_out, int out_size, void* d_ws, size_t ws_size,
                              hipStream_t stream) {
  const float* x   = (const float*)d_in[0];
  const int*   gid = (const int*)d_in[1];
  const float* W1  = (const float*)d_in[2];
  const float* b1  = (const float*)d_in[3];
  const float* W2  = (const float*)d_in[4];
  const float* b2  = (const float*)d_in[5];
  const float* Wg1 = (const float*)d_in[6];
  const float* bg1 = (const float*)d_in[7];
  const float* Wg2 = (const float*)d_in[8];
  const float* bg2 = (const float*)d_in[9];

  float* out = (float*)d_out;                       // routed output [B, OUT]
  float* gen = out + (size_t)Bn * OUTn;             // generic output [B, OUT]

  char* ws = (char*)d_ws;
  unsigned short* xb   = (unsigned short*)(ws);                  // 33,554,432 B
  unsigned short* W1t  = (unsigned short*)(ws + 33554432);       // 33,554,432 B [g][HID][IN]
  unsigned short* W2t  = (unsigned short*)(ws + 67108864);       //  8,388,608 B [g][OUT][HID]
  unsigned short* Wg1t = (unsigned short*)(ws + 75497472);       //  4,194,304 B [HID][IN]
  unsigned short* Wg2t = (unsigned short*)(ws + 79691776);       //  1,048,576 B [OUT][HID]
  unsigned short* h    = (unsigned short*)(ws + 80740352);       // 67,108,864 B [B][HID] bf16
  int* ridx            = (int*)(ws + 147849216);                 // 65,536 B
  int* meta            = (int*)(ws + 147914752);                 // 4 KiB
  int* cnt  = meta;
  int* goff = meta + 8;
  int* fill = meta + 16;
  int* ntl  = meta + 24;
  int2* desc = (int2*)(meta + 32);

  // routing
  hipMemsetAsync(meta, 0, 128, stream);
  hist_k<<<Bn / 256, 256, 0, stream>>>(gid, cnt);
  scan_desc_k<<<1, 64, 0, stream>>>(cnt, goff, fill, ntl, desc);
  scatter_k<<<Bn / 256, 256, 0, stream>>>(gid, goff, fill, ridx);

  // conversions
  conv_bf16_k<<<2048, 256, 0, stream>>>(x, xb, Bn * INn / 4);
  dim3 tb(32, 8);
  transpose_k<<<dim3(HIDn / 32, INn / 32, NGn), tb, 0, stream>>>(W1, W1t, INn, HIDn);
  transpose_k<<<dim3(OUTn / 32, HIDn / 32, NGn), tb, 0, stream>>>(W2, W2t, HIDn, OUTn);
  transpose_k<<<dim3(HIDn / 32, INn / 32, 1), tb, 0, stream>>>(Wg1, Wg1t, INn, HIDn);
  transpose_k<<<dim3(OUTn / 32, HIDn / 32, 1), tb, 0, stream>>>(Wg2, Wg2t, HIDn, OUTn);

  // generic path: h = relu(x@Wg1+bg1); gen = h@Wg2+bg2
  gemm_k<false, false, false, true><<<dim3(Bn / 128, HIDn / 128), 256, 0, stream>>>(
      xb, Wg1t, bg1, h, INn, HIDn, nullptr, nullptr, nullptr, nullptr, nullptr);
  gemm_k<false, false, false, false><<<dim3(Bn / 128, OUTn / 128), 256, 0, stream>>>(
      h, Wg2t, bg2, gen, HIDn, OUTn, nullptr, nullptr, nullptr, nullptr, nullptr);

  // routed path (compacted grouped GEMM): h = relu(gather(x)@W1[g]+b1[g]); out = scatter(h@W2[g]+b2[g])
  gemm_k<true, true, false, true><<<dim3(MAXT, HIDn / 128), 256, 0, stream>>>(
      xb, W1t, b1, h, INn, HIDn, cnt, goff, ntl, desc, ridx);
  gemm_k<true, false, true, false><<<dim3(MAXT, OUTn / 128), 256, 0, stream>>>(
      h, W2t, b2, out, HIDn, OUTn, cnt, goff, ntl, desc, ridx);
}

// Round 2
// 432.107 us; speedup vs baseline: 1.0461x; 1.0461x over previous
//
#include <hip/hip_runtime.h>
#include <cstdint>
#include <cstddef>

// Problem constants (from reference)
static constexpr int Bn   = 16384;
static constexpr int INn  = 1024;
static constexpr int HIDn = 2048;
static constexpr int OUTn = 256;
static constexpr int NGn  = 8;
static constexpr int MAXT = 136;   // max M-tiles over all groups: B/128 + G

typedef __attribute__((ext_vector_type(8))) __bf16 bf16x8;
typedef __attribute__((ext_vector_type(4))) float  f32x4;

__device__ __forceinline__ unsigned short f2bf(float f) {
  unsigned int u = __builtin_bit_cast(unsigned int, f);
  u += 0x7fffu + ((u >> 16) & 1u);   // RNE
  return (unsigned short)(u >> 16);
}

__device__ __forceinline__ void load_lds16(const void* g, void* l) {
  __builtin_amdgcn_global_load_lds(
      (const __attribute__((address_space(1))) unsigned int*)g,
      (__attribute__((address_space(3))) unsigned int*)l, 16, 0, 0);
}

// ---------------- routing kernels ----------------
__global__ void hist_k(const int* __restrict__ gid, int* __restrict__ cnt) {
  int i = blockIdx.x * blockDim.x + threadIdx.x;
  if (i < Bn) atomicAdd(&cnt[gid[i]], 1);
}

__global__ void scan_desc_k(const int* __restrict__ cnt, int* __restrict__ goff,
                            int* __restrict__ fill, int* __restrict__ ntiles,
                            int2* __restrict__ desc) {
  if (threadIdx.x == 0 && blockIdx.x == 0) {
    int o = 0, nt = 0;
    for (int g = 0; g < NGn; g++) {
      goff[g] = o;
      int c = cnt[g];
      for (int m = 0; m < c; m += 128) { desc[nt].x = g; desc[nt].y = m; nt++; }
      o += c;
      fill[g] = 0;
    }
    *ntiles = nt;
  }
}

__global__ void scatter_k(const int* __restrict__ gid, const int* __restrict__ goff,
                          int* __restrict__ fill, int* __restrict__ ridx) {
  int i = blockIdx.x * blockDim.x + threadIdx.x;
  if (i < Bn) {
    int g = gid[i];
    int pos = goff[g] + atomicAdd(&fill[g], 1);
    ridx[pos] = i;   // order nondeterministic, output values invariant
  }
}

// ---------------- conversion kernels ----------------
__global__ void conv_bf16_k(const float* __restrict__ src, unsigned short* __restrict__ dst,
                            int nvec) {  // nvec = elements/4
  int i = blockIdx.x * blockDim.x + threadIdx.x;
  int stride = gridDim.x * blockDim.x;
  for (; i < nvec; i += stride) {
    float4 v = ((const float4*)src)[i];
    uint2 o;
    o.x = (unsigned)f2bf(v.x) | ((unsigned)f2bf(v.y) << 16);
    o.y = (unsigned)f2bf(v.z) | ((unsigned)f2bf(v.w) << 16);
    ((uint2*)dst)[i] = o;
  }
}

// src [K][N] f32 row-major -> dst [N][K] bf16 row-major; blockIdx.z = batch
__global__ void transpose_k(const float* __restrict__ src, unsigned short* __restrict__ dst,
                            int K, int N) {
  __shared__ float t[32][33];
  size_t bo = (size_t)blockIdx.z * (size_t)K * (size_t)N;
  int n0 = blockIdx.x * 32, k0 = blockIdx.y * 32;
  #pragma unroll
  for (int i = 0; i < 32; i += 8)
    t[threadIdx.y + i][threadIdx.x] =
        src[bo + (size_t)(k0 + threadIdx.y + i) * N + n0 + threadIdx.x];
  __syncthreads();
  #pragma unroll
  for (int i = 0; i < 32; i += 8)
    dst[bo + (size_t)(n0 + threadIdx.y + i) * K + k0 + threadIdx.x] =
        f2bf(t[threadIdx.x][threadIdx.y + i]);
}

// ---------------- GEMM body ----------------
// C[M,N] = act(A[M,K](bf16) @ Bt[N,K]^T(bf16) [+ bias]), 128x128 tile, BK=64,
// 4 waves of 4x4 16x16x32 fragments. XOR-swizzled LDS (G4: stride-128B rows).
// OMODE 0: relu -> bf16 store (L1 / h).  OMODE 1: f32 partial store (split-K L2).
template <bool GROUPED, bool GATHER_A, int OMODE>
__device__ __forceinline__ void gemm_body(
    const unsigned short* __restrict__ A, const unsigned short* __restrict__ Bt,
    const float* __restrict__ bias, void* __restrict__ Cout, int K, int N,
    int ksplit, size_t zstride,
    const int* __restrict__ cnt, const int* __restrict__ goff,
    const int* __restrict__ ntiles, const int2* __restrict__ desc,
    const int* __restrict__ ridx) {
  // bijective XCD swizzle (m204) over the linearized (M-major, N-fast) grid:
  // each XCD gets a contiguous chunk -> in-flight blocks share A panels.
  int mtile, ntile;
  {
    int gx = gridDim.x;                       // N tiles (fast dim)
    int nwg = gx * gridDim.y;
    int l = blockIdx.y * gx + blockIdx.x;
    int q = nwg >> 3, rm = nwg & 7;
    int xcd = l & 7, i = l >> 3;
    int sl = (xcd < rm ? xcd * (q + 1) : rm * (q + 1) + (xcd - rm) * q) + i;
    mtile = sl / gx; ntile = sl - mtile * gx;
  }

  int row0, cnt_rem;
  if constexpr (GROUPED) {
    if (mtile >= *ntiles) return;
    int2 d = desc[mtile];
    int g = d.x;
    row0 = goff[g] + d.y;
    cnt_rem = cnt[g] - d.y;
    Bt += (size_t)g * (size_t)K * (size_t)N;
    if constexpr (OMODE == 0) bias += (size_t)g * (size_t)N;
  } else {
    row0 = mtile * 128;
    cnt_rem = 128;
  }
  int n0 = ntile * 128;
  const int kbase = blockIdx.z * ksplit;

  __shared__ __align__(16) char lds[32768];  // A: [0,16K) B^T: [16K,32K)

  int t = threadIdx.x;
  int lane = t & 63, wid = t >> 6;

  // staging source pointers (4 issues per matrix; row/col fixed across K-steps)
  const unsigned short* pA[4];
  const unsigned short* pB[4];
  #pragma unroll
  for (int i = 0; i < 4; i++) {
    int r = i * 32 + (t >> 3);             // logical tile row for this lane's 16B
    int cg = (t & 7) ^ (r & 7);            // inverse-swizzled column granule
    int rA;
    if constexpr (GROUPED) {
      int rcl = r < cnt_rem ? r : cnt_rem - 1;
      if constexpr (GATHER_A) rA = ridx[row0 + rcl];
      else                    rA = row0 + rcl;
    } else {
      rA = row0 + r;
    }
    pA[i] = A + (size_t)rA * K + cg * 8;
    pB[i] = Bt + (size_t)(n0 + r) * K + cg * 8;
  }

  int ln15 = lane & 15, l16 = lane >> 4, ln7 = lane & 7;
  int wm = wid >> 1, wn = wid & 1;
  int aoffb[4], boffb[4];
  #pragma unroll
  for (int m = 0; m < 4; m++) aoffb[m] = (wm * 64 + m * 16 + ln15) << 7;
  #pragma unroll
  for (int n = 0; n < 4; n++) boffb[n] = ((wn * 64 + n * 16 + ln15) << 7) + 16384;
  const int gsw0 = (l16 ^ ln7) << 4;
  const int gsw1 = ((4 + l16) ^ ln7) << 4;

  f32x4 acc[4][4];
  #pragma unroll
  for (int m = 0; m < 4; m++)
    #pragma unroll
    for (int n = 0; n < 4; n++) acc[m][n] = {0.f, 0.f, 0.f, 0.f};

  for (int kt = kbase; kt < kbase + ksplit; kt += 64) {
    __syncthreads();
    #pragma unroll
    for (int i = 0; i < 4; i++)
      load_lds16(pA[i] + kt, lds + i * 4096 + wid * 1024);
    #pragma unroll
    for (int i = 0; i < 4; i++)
      load_lds16(pB[i] + kt, lds + 16384 + i * 4096 + wid * 1024);
    __syncthreads();  // compiler drains vmcnt(0) before this barrier
    #pragma unroll
    for (int ks = 0; ks < 2; ks++) {
      const int gsw = ks ? gsw1 : gsw0;
      bf16x8 av[4], bv[4];
      #pragma unroll
      for (int m = 0; m < 4; m++) av[m] = *(const bf16x8*)(lds + aoffb[m] + gsw);
      #pragma unroll
      for (int n = 0; n < 4; n++) bv[n] = *(const bf16x8*)(lds + boffb[n] + gsw);
      #pragma unroll
      for (int m = 0; m < 4; m++)
        #pragma unroll
        for (int n = 0; n < 4; n++)
          acc[m][n] = __builtin_amdgcn_mfma_f32_16x16x32_bf16(av[m], bv[n], acc[m][n], 0, 0, 0);
    }
  }

  float biasv[4];
  if constexpr (OMODE == 0) {
    #pragma unroll
    for (int n = 0; n < 4; n++) biasv[n] = bias[n0 + wn * 64 + n * 16 + ln15];
  }
  float* Po = (float*)Cout + (size_t)blockIdx.z * zstride;

  #pragma unroll
  for (int m = 0; m < 4; m++) {
    #pragma unroll
    for (int j = 0; j < 4; j++) {
      int r = wm * 64 + m * 16 + l16 * 4 + j;   // C row within tile
      if (GROUPED && r >= cnt_rem) continue;
      size_t orow = (size_t)(row0 + r);
      #pragma unroll
      for (int n = 0; n < 4; n++) {
        int col = n0 + wn * 64 + n * 16 + ln15;
        if constexpr (OMODE == 0) {
          float v = acc[m][n][j] + biasv[n];
          v = v > 0.f ? v : 0.f;
          ((unsigned short*)Cout)[orow * N + col] = f2bf(v);
        } else {
          Po[orow * N + col] = acc[m][n][j];
        }
      }
    }
  }
}

// distinct names for rocprof disambiguation
__global__ __launch_bounds__(256, 2) void g1gen_k(
    const unsigned short* A, const unsigned short* Bt, const float* bias, void* C,
    int K, int N, int ksplit, size_t zs,
    const int* cnt, const int* goff, const int* ntl, const int2* desc, const int* ridx) {
  gemm_body<false, false, 0>(A, Bt, bias, C, K, N, ksplit, zs, cnt, goff, ntl, desc, ridx);
}
__global__ __launch_bounds__(256, 2) void g1rt_k(
    const unsigned short* A, const unsigned short* Bt, const float* bias, void* C,
    int K, int N, int ksplit, size_t zs,
    const int* cnt, const int* goff, const int* ntl, const int2* desc, const int* ridx) {
  gemm_body<true, true, 0>(A, Bt, bias, C, K, N, ksplit, zs, cnt, goff, ntl, desc, ridx);
}
__global__ __launch_bounds__(256, 2) void g2gen_k(
    const unsigned short* A, const unsigned short* Bt, const float* bias, void* C,
    int K, int N, int ksplit, size_t zs,
    const int* cnt, const int* goff, const int* ntl, const int2* desc, const int* ridx) {
  gemm_body<false, false, 1>(A, Bt, bias, C, K, N, ksplit, zs, cnt, goff, ntl, desc, ridx);
}
__global__ __launch_bounds__(256, 2) void g2rt_k(
    const unsigned short* A, const unsigned short* Bt, const float* bias, void* C,
    int K, int N, int ksplit, size_t zs,
    const int* cnt, const int* goff, const int* ntl, const int2* desc, const int* ridx) {
  gemm_body<true, false, 1>(A, Bt, bias, C, K, N, ksplit, zs, cnt, goff, ntl, desc, ridx);
}

// ---------------- split-K reduce kernels ----------------
__global__ void redu_gen_k(const float* __restrict__ P, const float* __restrict__ bias,
                           float* __restrict__ outp) {
  int i = blockIdx.x * 256 + threadIdx.x;   // float4 index over [B][OUT]
  float4 a = ((const float4*)P)[i];
  float4 b = ((const float4*)(P + (size_t)Bn * OUTn))[i];
  int c4 = (i & 63) << 2;                   // OUT/4 = 64 quads per row
  float4 bv = *(const float4*)(bias + c4);
  ((float4*)outp)[i] = {a.x + b.x + bv.x, a.y + b.y + bv.y,
                        a.z + b.z + bv.z, a.w + b.w + bv.w};
}

__global__ void redu_rt_k(const float* __restrict__ P, const float* __restrict__ b2,
                          float* __restrict__ outp,
                          const int* __restrict__ cnt, const int* __restrict__ goff,
                          const int* __restrict__ ntl, const int2* __restrict__ desc,
                          const int* __restrict__ ridx) {
  if ((int)blockIdx.x >= *ntl) return;
  int2 d = desc[blockIdx.x];
  int g = d.x;
  int row0 = goff[g] + d.y;
  int rem = cnt[g] - d.y; if (rem > 128) rem = 128;
  int t = threadIdx.x;
  int c4 = (t & 63) << 2;
  float4 bv = *(const float4*)(b2 + (size_t)g * OUTn + c4);
  for (int r = t >> 6; r < rem; r += 4) {
    size_t src = (size_t)(row0 + r) * OUTn + c4;
    float4 a = *(const float4*)(P + src);
    float4 b = *(const float4*)(P + (size_t)Bn * OUTn + src);
    int orow = ridx[row0 + r];
    *(float4*)(outp + (size_t)orow * OUTn + c4) =
        {a.x + b.x + bv.x, a.y + b.y + bv.y, a.z + b.z + bv.z, a.w + b.w + bv.w};
  }
}

// ---------------- launch ----------------
extern "C" void kernel_launch(void* const* d_in, const int* in_sizes, int n_in,
                              void* d_out, int out_size, void* d_ws, size_t ws_size,
                              hipStream_t stream) {
  const float* x   = (const float*)d_in[0];
  const int*   gid = (const int*)d_in[1];
  const float* W1  = (const float*)d_in[2];
  const float* b1  = (const float*)d_in[3];
  const float* W2  = (const float*)d_in[4];
  const float* b2  = (const float*)d_in[5];
  const float* Wg1 = (const float*)d_in[6];
  const float* bg1 = (const float*)d_in[7];
  const float* Wg2 = (const float*)d_in[8];
  const float* bg2 = (const float*)d_in[9];

  float* out = (float*)d_out;                       // routed output [B, OUT]
  float* gen = out + (size_t)Bn * OUTn;             // generic output [B, OUT]

  char* ws = (char*)d_ws;
  unsigned short* xb   = (unsigned short*)(ws);                  // 33,554,432 B
  unsigned short* W1t  = (unsigned short*)(ws + 33554432);       // 33,554,432 B [g][HID][IN]
  float*          Ppar = (float*)(ws + 33554432);                // overlays W1t after rtL1: 2x16Mx... = 33,554,432 B
  unsigned short* W2t  = (unsigned short*)(ws + 67108864);       //  8,388,608 B [g][OUT][HID]
  unsigned short* Wg1t = (unsigned short*)(ws + 75497472);       //  4,194,304 B [HID][IN]
  unsigned short* Wg2t = (unsigned short*)(ws + 79691776);       //  1,048,576 B [OUT][HID]
  unsigned short* h    = (unsigned short*)(ws + 80740352);       // 67,108,864 B [B][HID] bf16
  int* ridx            = (int*)(ws + 147849216);                 // 65,536 B
  int* meta            = (int*)(ws + 147914752);                 // 4 KiB
  int* cnt  = meta;
  int* goff = meta + 8;
  int* fill = meta + 16;
  int* ntl  = meta + 24;
  int2* desc = (int2*)(meta + 32);

  const size_t zstr = (size_t)Bn * OUTn;            // split-K partial stride (elems)

  // routing
  hipMemsetAsync(meta, 0, 128, stream);
  hist_k<<<Bn / 256, 256, 0, stream>>>(gid, cnt);
  scan_desc_k<<<1, 64, 0, stream>>>(cnt, goff, fill, ntl, desc);
  scatter_k<<<Bn / 256, 256, 0, stream>>>(gid, goff, fill, ridx);

  // conversions
  conv_bf16_k<<<2048, 256, 0, stream>>>(x, xb, Bn * INn / 4);
  dim3 tb(32, 8);
  transpose_k<<<dim3(HIDn / 32, INn / 32, NGn), tb, 0, stream>>>(W1, W1t, INn, HIDn);
  transpose_k<<<dim3(OUTn / 32, HIDn / 32, NGn), tb, 0, stream>>>(W2, W2t, HIDn, OUTn);
  transpose_k<<<dim3(HIDn / 32, INn / 32, 1), tb, 0, stream>>>(Wg1, Wg1t, INn, HIDn);
  transpose_k<<<dim3(OUTn / 32, HIDn / 32, 1), tb, 0, stream>>>(Wg2, Wg2t, HIDn, OUTn);

  // ---- routed path first (so Ppar can overlay W1t afterwards) ----
  // h = relu(gather(x) @ W1[g] + b1[g])   grid: (Ntiles fast, Mtiles)
  g1rt_k<<<dim3(HIDn / 128, MAXT), 256, 0, stream>>>(
      xb, W1t, b1, h, INn, HIDn, INn, 0, cnt, goff, ntl, desc, ridx);
  // split-K=2 partials: P[z] = h @ W2[g]   (overlays W1t region)
  g2rt_k<<<dim3(OUTn / 128, MAXT, 2), 256, 0, stream>>>(
      h, W2t, nullptr, Ppar, HIDn, OUTn, HIDn / 2, zstr, cnt, goff, ntl, desc, ridx);
  redu_rt_k<<<MAXT, 256, 0, stream>>>(Ppar, b2, out, cnt, goff, ntl, desc, ridx);

  // ---- generic path ----
  g1gen_k<<<dim3(HIDn / 128, Bn / 128), 256, 0, stream>>>(
      xb, Wg1t, bg1, h, INn, HIDn, INn, 0, nullptr, nullptr, nullptr, nullptr, nullptr);
  g2gen_k<<<dim3(OUTn / 128, Bn / 128, 2), 256, 0, stream>>>(
      h, Wg2t, nullptr, Ppar, HIDn, OUTn, HIDn / 2, zstr, nullptr, nullptr, nullptr, nullptr, nullptr);
  redu_gen_k<<<(Bn * OUTn / 4) / 256, 256, 0, stream>>>(Ppar, bg2, gen);
}

// Round 3
// 290.367 us; speedup vs baseline: 1.5567x; 1.4881x over previous
//
#include <hip/hip_runtime.h>
#include <cstdint>
#include <cstddef>

// Problem constants (from reference)
static constexpr int Bn   = 16384;
static constexpr int INn  = 1024;
static constexpr int HIDn = 2048;
static constexpr int OUTn = 256;
static constexpr int NGn  = 8;
static constexpr int MAXT = 136;   // max M-tiles over all groups: B/128 + G
static constexpr int NBLK = Bn / 256;  // 64 routing blocks

typedef __attribute__((ext_vector_type(8))) __bf16 bf16x8;
typedef __attribute__((ext_vector_type(4))) float  f32x4;

__device__ __forceinline__ unsigned short f2bf(float f) {
  unsigned int u = __builtin_bit_cast(unsigned int, f);
  u += 0x7fffu + ((u >> 16) & 1u);   // RNE
  return (unsigned short)(u >> 16);
}

__device__ __forceinline__ void load_lds16(const void* g, void* l) {
  __builtin_amdgcn_global_load_lds(
      (const __attribute__((address_space(1))) unsigned int*)g,
      (__attribute__((address_space(3))) unsigned int*)l, 16, 0, 0);
}

// ---------------- routing: deterministic counting sort, no global atomics ----
// Phase 1: per-block histogram (LDS atomics only).
__global__ void blkhist_k(const int* __restrict__ gid, int* __restrict__ blk_cnt) {
  __shared__ int h[NGn];
  if (threadIdx.x < NGn) h[threadIdx.x] = 0;
  __syncthreads();
  atomicAdd(&h[gid[blockIdx.x * 256 + threadIdx.x]], 1);
  __syncthreads();
  if (threadIdx.x < NGn) blk_cnt[blockIdx.x * NGn + threadIdx.x] = h[threadIdx.x];
}

// Phase 2: one block of 512 threads: group totals, group offsets, tile descs,
// and per-(block,group) base offsets.
__global__ void scan_desc_k(const int* __restrict__ blk_cnt, int* __restrict__ cnt,
                            int* __restrict__ goff, int* __restrict__ ntl,
                            int2* __restrict__ desc, int* __restrict__ bbase) {
  __shared__ int s[NGn][NBLK];
  __shared__ int tot[NGn], go[NGn];
  int t = threadIdx.x;             // 512 = 8 groups x 64 blocks
  int g = t >> 6, b = t & 63;
  s[g][b] = blk_cnt[b * NGn + g];
  __syncthreads();
  int pre = 0;
  for (int b2 = 0; b2 < b; b2++) pre += s[g][b2];
  if (b == 63) tot[g] = pre + s[g][63];
  __syncthreads();
  if (t == 0) {
    int o = 0, nt = 0;
    for (int gg = 0; gg < NGn; gg++) {
      go[gg] = o; goff[gg] = o; cnt[gg] = tot[gg];
      for (int m = 0; m < tot[gg]; m += 128) { desc[nt].x = gg; desc[nt].y = m; nt++; }
      o += tot[gg];
    }
    *ntl = nt;
  }
  __syncthreads();
  bbase[b * NGn + g] = go[g] + pre;
}

// Phase 3: stable placement via wave ballot rank (deterministic).
__global__ void place_k(const int* __restrict__ gid, const int* __restrict__ bbase,
                        int* __restrict__ ridx) {
  __shared__ int wcnt[4][NGn];
  int i = blockIdx.x * 256 + threadIdx.x;
  int g = gid[i];
  int lane = threadIdx.x & 63, w = threadIdx.x >> 6;
  unsigned long long mym = 0;
  #pragma unroll
  for (int grp = 0; grp < NGn; grp++) {
    unsigned long long m = __ballot(g == grp);
    if (lane == 0) wcnt[w][grp] = __popcll(m);
    if (g == grp) mym = m;
  }
  __syncthreads();
  int wrank = __popcll(mym & ((1ull << lane) - 1ull));
  int base = 0;
  for (int w2 = 0; w2 < w; w2++) base += wcnt[w2][g];
  ridx[bbase[blockIdx.x * NGn + g] + base + wrank] = i;
}

// ---------------- conversion kernels ----------------
__global__ void conv_bf16_k(const float* __restrict__ src, unsigned short* __restrict__ dst,
                            int nvec) {  // nvec = elements/4
  int i = blockIdx.x * blockDim.x + threadIdx.x;
  int stride = gridDim.x * blockDim.x;
  for (; i < nvec; i += stride) {
    float4 v = ((const float4*)src)[i];
    uint2 o;
    o.x = (unsigned)f2bf(v.x) | ((unsigned)f2bf(v.y) << 16);
    o.y = (unsigned)f2bf(v.z) | ((unsigned)f2bf(v.w) << 16);
    ((uint2*)dst)[i] = o;
  }
}

// src [K][N] f32 row-major -> dst [N][K] bf16 row-major; blockIdx.z = batch
__global__ void transpose_k(const float* __restrict__ src, unsigned short* __restrict__ dst,
                            int K, int N) {
  __shared__ float t[32][33];
  size_t bo = (size_t)blockIdx.z * (size_t)K * (size_t)N;
  int n0 = blockIdx.x * 32, k0 = blockIdx.y * 32;
  #pragma unroll
  for (int i = 0; i < 32; i += 8)
    t[threadIdx.y + i][threadIdx.x] =
        src[bo + (size_t)(k0 + threadIdx.y + i) * N + n0 + threadIdx.x];
  __syncthreads();
  #pragma unroll
  for (int i = 0; i < 32; i += 8)
    dst[bo + (size_t)(n0 + threadIdx.y + i) * K + k0 + threadIdx.x] =
        f2bf(t[threadIdx.x][threadIdx.y + i]);
}

// ---------------- GEMM body ----------------
// C[M,N] = act(A[M,K](bf16) @ Bt[N,K]^T(bf16) [+ bias]), 128x128 tile, BK=64,
// 4 waves of 4x4 16x16x32 fragments. XOR-swizzled LDS (G4: stride-128B rows).
// OMODE 0: relu -> bf16 store (L1 / h).  OMODE 1: f32 partial store (split-K L2).
template <bool GROUPED, bool GATHER_A, int OMODE>
__device__ __forceinline__ void gemm_body(
    const unsigned short* __restrict__ A, const unsigned short* __restrict__ Bt,
    const float* __restrict__ bias, void* __restrict__ Cout, int K, int N,
    int ksplit, size_t zstride,
    const int* __restrict__ cnt, const int* __restrict__ goff,
    const int* __restrict__ ntiles, const int2* __restrict__ desc,
    const int* __restrict__ ridx) {
  // bijective XCD swizzle (m204) over the linearized (M-major, N-fast) grid.
  int mtile, ntile;
  {
    int gx = gridDim.x;                       // N tiles (fast dim)
    int nwg = gx * gridDim.y;
    int l = blockIdx.y * gx + blockIdx.x;
    int q = nwg >> 3, rm = nwg & 7;
    int xcd = l & 7, i = l >> 3;
    int sl = (xcd < rm ? xcd * (q + 1) : rm * (q + 1) + (xcd - rm) * q) + i;
    mtile = sl / gx; ntile = sl - mtile * gx;
  }

  int row0, cnt_rem;
  if constexpr (GROUPED) {
    if (mtile >= *ntiles) return;
    int2 d = desc[mtile];
    int g = d.x;
    row0 = goff[g] + d.y;
    cnt_rem = cnt[g] - d.y;
    Bt += (size_t)g * (size_t)K * (size_t)N;
    if constexpr (OMODE == 0) bias += (size_t)g * (size_t)N;
  } else {
    row0 = mtile * 128;
    cnt_rem = 128;
  }
  int n0 = ntile * 128;
  const int kbase = blockIdx.z * ksplit;

  __shared__ __align__(16) char lds[32768];  // A: [0,16K) B^T: [16K,32K)

  int t = threadIdx.x;
  int lane = t & 63, wid = t >> 6;

  // staging source pointers (4 issues per matrix; row/col fixed across K-steps)
  const unsigned short* pA[4];
  const unsigned short* pB[4];
  #pragma unroll
  for (int i = 0; i < 4; i++) {
    int r = i * 32 + (t >> 3);             // logical tile row for this lane's 16B
    int cg = (t & 7) ^ (r & 7);            // inverse-swizzled column granule
    int rA;
    if constexpr (GROUPED) {
      int rcl = r < cnt_rem ? r : cnt_rem - 1;
      if constexpr (GATHER_A) rA = ridx[row0 + rcl];
      else                    rA = row0 + rcl;
    } else {
      rA = row0 + r;
    }
    pA[i] = A + (size_t)rA * K + cg * 8;
    pB[i] = Bt + (size_t)(n0 + r) * K + cg * 8;
  }

  int ln15 = lane & 15, l16 = lane >> 4, ln7 = lane & 7;
  int wm = wid >> 1, wn = wid & 1;
  int aoffb[4], boffb[4];
  #pragma unroll
  for (int m = 0; m < 4; m++) aoffb[m] = (wm * 64 + m * 16 + ln15) << 7;
  #pragma unroll
  for (int n = 0; n < 4; n++) boffb[n] = ((wn * 64 + n * 16 + ln15) << 7) + 16384;
  const int gsw0 = (l16 ^ ln7) << 4;
  const int gsw1 = ((4 + l16) ^ ln7) << 4;

  f32x4 acc[4][4];
  #pragma unroll
  for (int m = 0; m < 4; m++)
    #pragma unroll
    for (int n = 0; n < 4; n++) acc[m][n] = {0.f, 0.f, 0.f, 0.f};

  for (int kt = kbase; kt < kbase + ksplit; kt += 64) {
    __syncthreads();
    #pragma unroll
    for (int i = 0; i < 4; i++)
      load_lds16(pA[i] + kt, lds + i * 4096 + wid * 1024);
    #pragma unroll
    for (int i = 0; i < 4; i++)
      load_lds16(pB[i] + kt, lds + 16384 + i * 4096 + wid * 1024);
    __syncthreads();  // compiler drains vmcnt(0) before this barrier
    #pragma unroll
    for (int ks = 0; ks < 2; ks++) {
      const int gsw = ks ? gsw1 : gsw0;
      bf16x8 av[4], bv[4];
      #pragma unroll
      for (int m = 0; m < 4; m++) av[m] = *(const bf16x8*)(lds + aoffb[m] + gsw);
      #pragma unroll
      for (int n = 0; n < 4; n++) bv[n] = *(const bf16x8*)(lds + boffb[n] + gsw);
      #pragma unroll
      for (int m = 0; m < 4; m++)
        #pragma unroll
        for (int n = 0; n < 4; n++)
          acc[m][n] = __builtin_amdgcn_mfma_f32_16x16x32_bf16(av[m], bv[n], acc[m][n], 0, 0, 0);
    }
  }

  float biasv[4];
  if constexpr (OMODE == 0) {
    #pragma unroll
    for (int n = 0; n < 4; n++) biasv[n] = bias[n0 + wn * 64 + n * 16 + ln15];
  }
  float* Po = (float*)Cout + (size_t)blockIdx.z * zstride;

  #pragma unroll
  for (int m = 0; m < 4; m++) {
    #pragma unroll
    for (int j = 0; j < 4; j++) {
      int r = wm * 64 + m * 16 + l16 * 4 + j;   // C row within tile
      if (GROUPED && r >= cnt_rem) continue;
      size_t orow = (size_t)(row0 + r);
      #pragma unroll
      for (int n = 0; n < 4; n++) {
        int col = n0 + wn * 64 + n * 16 + ln15;
        if constexpr (OMODE == 0) {
          float v = acc[m][n][j] + biasv[n];
          v = v > 0.f ? v : 0.f;
          ((unsigned short*)Cout)[orow * N + col] = f2bf(v);
        } else {
          Po[orow * N + col] = acc[m][n][j];
        }
      }
    }
  }
}

// distinct names for rocprof disambiguation
__global__ __launch_bounds__(256, 2) void g1gen_k(
    const unsigned short* A, const unsigned short* Bt, const float* bias, void* C,
    int K, int N, int ksplit, size_t zs,
    const int* cnt, const int* goff, const int* ntl, const int2* desc, const int* ridx) {
  gemm_body<false, false, 0>(A, Bt, bias, C, K, N, ksplit, zs, cnt, goff, ntl, desc, ridx);
}
__global__ __launch_bounds__(256, 2) void g1rt_k(
    const unsigned short* A, const unsigned short* Bt, const float* bias, void* C,
    int K, int N, int ksplit, size_t zs,
    const int* cnt, const int* goff, const int* ntl, const int2* desc, const int* ridx) {
  gemm_body<true, true, 0>(A, Bt, bias, C, K, N, ksplit, zs, cnt, goff, ntl, desc, ridx);
}
__global__ __launch_bounds__(256, 2) void g2gen_k(
    const unsigned short* A, const unsigned short* Bt, const float* bias, void* C,
    int K, int N, int ksplit, size_t zs,
    const int* cnt, const int* goff, const int* ntl, const int2* desc, const int* ridx) {
  gemm_body<false, false, 1>(A, Bt, bias, C, K, N, ksplit, zs, cnt, goff, ntl, desc, ridx);
}
__global__ __launch_bounds__(256, 2) void g2rt_k(
    const unsigned short* A, const unsigned short* Bt, const float* bias, void* C,
    int K, int N, int ksplit, size_t zs,
    const int* cnt, const int* goff, const int* ntl, const int2* desc, const int* ridx) {
  gemm_body<true, false, 1>(A, Bt, bias, C, K, N, ksplit, zs, cnt, goff, ntl, desc, ridx);
}

// ---------------- split-K reduce kernels ----------------
__global__ void redu_gen_k(const float* __restrict__ P, const float* __restrict__ bias,
                           float* __restrict__ outp) {
  int i = blockIdx.x * 256 + threadIdx.x;   // float4 index over [B][OUT]
  float4 a = ((const float4*)P)[i];
  float4 b = ((const float4*)(P + (size_t)Bn * OUTn))[i];
  int c4 = (i & 63) << 2;                   // OUT/4 = 64 quads per row
  float4 bv = *(const float4*)(bias + c4);
  ((float4*)outp)[i] = {a.x + b.x + bv.x, a.y + b.y + bv.y,
                        a.z + b.z + bv.z, a.w + b.w + bv.w};
}

__global__ void redu_rt_k(const float* __restrict__ P, const float* __restrict__ b2,
                          float* __restrict__ outp,
                          const int* __restrict__ cnt, const int* __restrict__ goff,
                          const int* __restrict__ ntl, const int2* __restrict__ desc,
                          const int* __restrict__ ridx) {
  if ((int)blockIdx.x >= *ntl) return;
  int2 d = desc[blockIdx.x];
  int g = d.x;
  int row0 = goff[g] + d.y;
  int rem = cnt[g] - d.y; if (rem > 128) rem = 128;
  int t = threadIdx.x;
  int c4 = (t & 63) << 2;
  float4 bv = *(const float4*)(b2 + (size_t)g * OUTn + c4);
  for (int r = t >> 6; r < rem; r += 4) {
    size_t src = (size_t)(row0 + r) * OUTn + c4;
    float4 a = *(const float4*)(P + src);
    float4 b = *(const float4*)(P + (size_t)Bn * OUTn + src);
    int orow = ridx[row0 + r];
    *(float4*)(outp + (size_t)orow * OUTn + c4) =
        {a.x + b.x + bv.x, a.y + b.y + bv.y, a.z + b.z + bv.z, a.w + b.w + bv.w};
  }
}

// ---------------- launch ----------------
extern "C" void kernel_launch(void* const* d_in, const int* in_sizes, int n_in,
                              void* d_out, int out_size, void* d_ws, size_t ws_size,
                              hipStream_t stream) {
  const float* x   = (const float*)d_in[0];
  const int*   gid = (const int*)d_in[1];
  const float* W1  = (const float*)d_in[2];
  const float* b1  = (const float*)d_in[3];
  const float* W2  = (const float*)d_in[4];
  const float* b2  = (const float*)d_in[5];
  const float* Wg1 = (const float*)d_in[6];
  const float* bg1 = (const float*)d_in[7];
  const float* Wg2 = (const float*)d_in[8];
  const float* bg2 = (const float*)d_in[9];

  float* out = (float*)d_out;                       // routed output [B, OUT]
  float* gen = out + (size_t)Bn * OUTn;             // generic output [B, OUT]

  char* ws = (char*)d_ws;
  unsigned short* xb   = (unsigned short*)(ws);                  // 33,554,432 B
  unsigned short* W1t  = (unsigned short*)(ws + 33554432);       // 33,554,432 B [g][HID][IN]
  float*          Ppar = (float*)(ws + 33554432);                // overlays W1t after rtL1
  unsigned short* W2t  = (unsigned short*)(ws + 67108864);       //  8,388,608 B [g][OUT][HID]
  unsigned short* Wg1t = (unsigned short*)(ws + 75497472);       //  4,194,304 B [HID][IN]
  unsigned short* Wg2t = (unsigned short*)(ws + 79691776);       //  1,048,576 B [OUT][HID]
  unsigned short* h    = (unsigned short*)(ws + 80740352);       // 67,108,864 B [B][HID] bf16
  int* ridx            = (int*)(ws + 147849216);                 // 65,536 B
  int* meta            = (int*)(ws + 147914752);                 // 8 KiB
  int* cnt  = meta;            // 8
  int* goff = meta + 8;        // 8
  int* ntl  = meta + 16;       // 1
  int2* desc = (int2*)(meta + 32);   // 136*2 ints
  int* blk_cnt = meta + 512;   // 512
  int* bbase   = meta + 1024;  // 512

  const size_t zstr = (size_t)Bn * OUTn;            // split-K partial stride (elems)

  // routing: deterministic counting sort (no global atomics)
  blkhist_k<<<NBLK, 256, 0, stream>>>(gid, blk_cnt);
  scan_desc_k<<<1, 512, 0, stream>>>(blk_cnt, cnt, goff, ntl, desc, bbase);
  place_k<<<NBLK, 256, 0, stream>>>(gid, bbase, ridx);

  // conversions
  conv_bf16_k<<<2048, 256, 0, stream>>>(x, xb, Bn * INn / 4);
  dim3 tb(32, 8);
  transpose_k<<<dim3(HIDn / 32, INn / 32, NGn), tb, 0, stream>>>(W1, W1t, INn, HIDn);
  transpose_k<<<dim3(OUTn / 32, HIDn / 32, NGn), tb, 0, stream>>>(W2, W2t, HIDn, OUTn);
  transpose_k<<<dim3(HIDn / 32, INn / 32, 1), tb, 0, stream>>>(Wg1, Wg1t, INn, HIDn);
  transpose_k<<<dim3(OUTn / 32, HIDn / 32, 1), tb, 0, stream>>>(Wg2, Wg2t, HIDn, OUTn);

  // ---- routed path first (so Ppar can overlay W1t afterwards) ----
  g1rt_k<<<dim3(HIDn / 128, MAXT), 256, 0, stream>>>(
      xb, W1t, b1, h, INn, HIDn, INn, 0, cnt, goff, ntl, desc, ridx);
  g2rt_k<<<dim3(OUTn / 128, MAXT, 2), 256, 0, stream>>>(
      h, W2t, nullptr, Ppar, HIDn, OUTn, HIDn / 2, zstr, cnt, goff, ntl, desc, ridx);
  redu_rt_k<<<MAXT, 256, 0, stream>>>(Ppar, b2, out, cnt, goff, ntl, desc, ridx);

  // ---- generic path ----
  g1gen_k<<<dim3(HIDn / 128, Bn / 128), 256, 0, stream>>>(
      xb, Wg1t, bg1, h, INn, HIDn, INn, 0, nullptr, nullptr, nullptr, nullptr, nullptr);
  g2gen_k<<<dim3(OUTn / 128, Bn / 128, 2), 256, 0, stream>>>(
      h, Wg2t, nullptr, Ppar, HIDn, OUTn, HIDn / 2, zstr, nullptr, nullptr, nullptr, nullptr, nullptr);
  redu_gen_k<<<(Bn * OUTn / 4) / 256, 256, 0, stream>>>(Ppar, bg2, gen);
}